// Round 5
// baseline (293.588 us; speedup 1.0000x reference)
//
#include <hip/hip_runtime.h>
#include <math.h>

typedef __bf16 bf16_t;
typedef __bf16 bf16x8 __attribute__((ext_vector_type(8)));
typedef float f32x4 __attribute__((ext_vector_type(4)));

#define B_INS 8192
#define N_INS 16384
#define D 128
#define BP 256
#define P 256
#define NP 512

// exp(l-10) with l = dot*10  ==  exp2(dot*C1 - C1), C1 = 10*log2(e)
#define C1_CONST 14.426950408889634f

// ---------------- workspace layout (floats) ----------------
#define WS_ACC 0
#define WS_S 8
#define WS_POS (8 + 16384)
#define WS_SP (8 + 2 * 16384)
#define WS_PP (WS_SP + BP * NP)
#define WS_ZERO_FLOATS (WS_PP + BP * NP)
#define EMB_I_BYTE ((((WS_ZERO_FLOATS) * 4 + 15) / 16) * 16)
#define EMB_P_BYTE (EMB_I_BYTE + N_INS * D * 2)

// Panel layout: global row i, k -> panel p=i>>7, r=i&127, g=k>>3, j=k&7
// elem offset = (p<<14) + (g<<10) + (r<<3) + j. One panel = 16384 elems = 32 KB.
// Fragment loads: 16 tx-lanes at stride 16B -> contiguous 256B runs, coalesced.

// ---------------- normalize kernels (write panel layout) ----------------
__global__ __launch_bounds__(256) void norm_ins_k(const float* __restrict__ v1,
                                                  const float* __restrict__ v2,
                                                  bf16_t* __restrict__ embI) {
    int w = threadIdx.x >> 6, lane = threadIdx.x & 63;
    int i = blockIdx.x * 4 + w;
    const float* src = (i < B_INS) ? (v1 + (size_t)i * D) : (v2 + (size_t)(i - B_INS) * D);
    float2 v = *(const float2*)(src + lane * 2);
    float ss = v.x * v.x + v.y * v.y;
#pragma unroll
    for (int off = 32; off >= 1; off >>= 1) ss += __shfl_xor(ss, off, 64);
    float inv = 1.0f / fmaxf(sqrtf(ss), 1e-12f);
    union { bf16_t b[2]; unsigned u; } pk;
    pk.b[0] = (bf16_t)(v.x * inv);
    pk.b[1] = (bf16_t)(v.y * inv);
    // k = 2*lane: g = lane>>2, j = 2*(lane&3)
    size_t off = ((size_t)(i >> 7) << 14) + ((size_t)(lane >> 2) << 10) +
                 ((size_t)(i & 127) << 3) + ((lane & 3) << 1);
    *(unsigned*)(embI + off) = pk.u;
}

__global__ __launch_bounds__(256) void norm_patch_k(const float* __restrict__ v1,
                                                    const float* __restrict__ v2,
                                                    bf16_t* __restrict__ embP) {
    __shared__ float L[128][65];
    __shared__ float ps[4][64];
    __shared__ float invs[64];
    int t = threadIdx.x;
    int bx = blockIdx.x;
    int b = bx >> 3, h = (bx >> 2) & 1, chunk = bx & 3;
    int i0 = chunk * 64;
    const float* src = ((h == 0) ? v1 : v2) + (size_t)b * D * P;

#pragma unroll
    for (int it = 0; it < 8; it++) {
        int fi = it * 256 + t;
        int d = fi >> 4, c4 = fi & 15;
        float4 v = *(const float4*)(src + (size_t)d * P + i0 + c4 * 4);
        L[d][c4 * 4 + 0] = v.x;
        L[d][c4 * 4 + 1] = v.y;
        L[d][c4 * 4 + 2] = v.z;
        L[d][c4 * 4 + 3] = v.w;
    }
    __syncthreads();
    {
        int col = t & 63, part = t >> 6;
        float ss = 0.f;
#pragma unroll 8
        for (int d = part * 32; d < part * 32 + 32; d++) { float x = L[d][col]; ss += x * x; }
        ps[part][col] = ss;
    }
    __syncthreads();
    if (t < 64) {
        float n2 = ps[0][t] + ps[1][t] + ps[2][t] + ps[3][t];
        invs[t] = 1.0f / fmaxf(sqrtf(n2), 1e-12f);
    }
    __syncthreads();
#pragma unroll
    for (int it = 0; it < 16; it++) {
        int idx = it * 256 + t;
        int pc = idx & 63, ic = idx >> 6;
        int d = pc * 2;
        float inv = invs[ic];
        union { bf16_t b[2]; unsigned u; } pk;
        pk.b[0] = (bf16_t)(L[d][ic] * inv);
        pk.b[1] = (bf16_t)(L[d + 1][ic] * inv);
        int iLoc = h * P + i0 + ic;   // row within batch, [0,512)
        size_t off = ((size_t)b << 16) + ((size_t)(iLoc >> 7) << 14) +
                     ((size_t)(pc >> 2) << 10) + ((size_t)(iLoc & 127) << 3) +
                     ((pc & 3) << 1);
        *(unsigned*)(embP + off) = pk.u;
    }
}

// ---------------- barrier-free register-streaming Gram body ----------------
// Wave handles 64 rows (rh half of panel R) x 64 cols (ch half of panel C).
// A frags held in 64 VGPRs across the C-stream; B frags streamed from L2.
// Per-nt epilogue keeps acc live-range to 16 VGPRs.
__device__ __forceinline__ void gram_quadrant(const bf16x8 af[4][4],
                                              const bf16_t* __restrict__ bbase,
                                              bool isDiag, bool isPos,
                                              int rowBase, int colBase,
                                              int rh, int ch, int tx, int q,
                                              float rowS[16],
                                              float* __restrict__ S,
                                              float* __restrict__ pos) {
    float colS[4] = {0.f, 0.f, 0.f, 0.f};
#pragma unroll
    for (int nt = 0; nt < 4; nt++) {
        bf16x8 bf[4];
#pragma unroll
        for (int ks = 0; ks < 4; ks++)
            bf[ks] = *(const bf16x8*)(bbase + (((ks << 2) + q) << 10) + (nt << 7));
        f32x4 acc[4];
#pragma unroll
        for (int rt = 0; rt < 4; rt++) acc[rt] = (f32x4){0.f, 0.f, 0.f, 0.f};
#pragma unroll
        for (int ks = 0; ks < 4; ks++)
#pragma unroll
            for (int rt = 0; rt < 4; rt++)
                acc[rt] = __builtin_amdgcn_mfma_f32_16x16x32_bf16(
                    af[rt][ks], bf[ks], acc[rt], 0, 0, 0);
#pragma unroll
        for (int rt = 0; rt < 4; rt++) {
#pragma unroll
            for (int reg = 0; reg < 4; reg++) {
                float e = __builtin_amdgcn_exp2f(
                    fmaf(acc[rt][reg], C1_CONST, -C1_CONST));
                if (isDiag) {
                    int inRow = rh * 64 + rt * 16 + q * 4 + reg;
                    int inCol = ch * 64 + nt * 16 + tx;
                    e = (inRow == inCol) ? 0.f : e;
                }
                rowS[rt * 4 + reg] += e;
                colS[nt] += e;
            }
        }
        if (isPos && ch == rh) {
            int reg = tx - q * 4;
            if (reg >= 0 && reg < 4) {
                float pl = acc[nt][reg] * 10.0f;   // rt == nt diagonal fragment
                atomicAdd(&pos[rowBase + rh * 64 + nt * 16 + tx], pl);
                atomicAdd(&pos[colBase + rh * 64 + nt * 16 + tx], pl);
            }
        }
    }
    if (!isDiag) {
#pragma unroll
        for (int i = 0; i < 4; i++) {
            colS[i] += __shfl_xor(colS[i], 16, 64);
            colS[i] += __shfl_xor(colS[i], 32, 64);
        }
        if (q == 0) {
#pragma unroll
            for (int nt = 0; nt < 4; nt++)
                atomicAdd(&S[colBase + ch * 64 + nt * 16 + tx], colS[nt]);
        }
    }
}

__device__ __forceinline__ void flush_rowS(float rowS[16], int rowBase,
                                           int rh, int tx, int q,
                                           float* __restrict__ S) {
#pragma unroll
    for (int off = 1; off <= 8; off <<= 1)
#pragma unroll
        for (int i = 0; i < 16; i++) rowS[i] += __shfl_xor(rowS[i], off, 16);
    if (tx == 0) {
#pragma unroll
        for (int rt = 0; rt < 4; rt++)
#pragma unroll
            for (int reg = 0; reg < 4; reg++)
                atomicAdd(&S[rowBase + rh * 64 + rt * 16 + q * 4 + reg],
                          rowS[rt * 4 + reg]);
    }
}

__device__ __forceinline__ void load_afrags(const bf16_t* __restrict__ abase,
                                            int rh, int tx, int q, bf16x8 af[4][4]) {
    const bf16_t* a = abase + ((rh * 64 + tx) << 3);
#pragma unroll
    for (int rt = 0; rt < 4; rt++)
#pragma unroll
        for (int ks = 0; ks < 4; ks++)
            af[rt][ks] = *(const bf16x8*)(a + (((ks << 2) + q) << 10) + (rt << 7));
}

// ---------------- instance CE: no LDS, no barriers ----------------
__global__ __launch_bounds__(256) void ins_panel_k(const bf16_t* __restrict__ emb,
                                                   float* __restrict__ S,
                                                   float* __restrict__ pos) {
    int t = threadIdx.x, w = t >> 6, lane = t & 63;
    int tx = lane & 15, q = lane >> 4;
    int rh = w & 1, ch = w >> 1;

    // decode: octet k has 8 panels x (16-k) chunks
    int bid = blockIdx.x, k = 0, cum = 0;
    while (bid >= cum + 8 * (16 - k)) { cum += 8 * (16 - k); k++; }
    int rem = bid - cum;
    int cc = 16 - k;
    int R = 8 * k + rem / cc;
    int ci = rem - (rem / cc) * cc;
    int c0 = R + ci * 8;
    int ntiles = min(8, 128 - c0);
    int rowBase = R * 128;

    bf16x8 af[4][4];
    load_afrags(emb + ((size_t)R << 14), rh, tx, q, af);

    float rowS[16];
#pragma unroll
    for (int i = 0; i < 16; i++) rowS[i] = 0.f;

    for (int ti = 0; ti < ntiles; ti++) {
        int C = c0 + ti;
        const bf16_t* bbase = emb + ((size_t)C << 14) + ((ch * 64 + tx) << 3);
        gram_quadrant(af, bbase, C == R, C == R + 64, rowBase, C * 128,
                      rh, ch, tx, q, rowS, S, pos);
    }
    flush_rowS(rowS, rowBase, rh, tx, q, S);
}

// ---------------- patch CE: block = (batch, row panel), stream C = R..3 ----------------
__global__ __launch_bounds__(256) void patch_panel_k(const bf16_t* __restrict__ embP,
                                                     float* __restrict__ Sp,
                                                     float* __restrict__ posp) {
    int t = threadIdx.x, w = t >> 6, lane = t & 63;
    int tx = lane & 15, q = lane >> 4;
    int rh = w & 1, ch = w >> 1;
    int R = blockIdx.x & 3, b = blockIdx.x >> 2;
    const bf16_t* base = embP + ((size_t)b << 16);
    float* Sb = Sp + (size_t)b * NP;
    float* pb = posp + (size_t)b * NP;

    bf16x8 af[4][4];
    load_afrags(base + ((size_t)R << 14), rh, tx, q, af);

    float rowS[16];
#pragma unroll
    for (int i = 0; i < 16; i++) rowS[i] = 0.f;

    for (int C = R; C < 4; C++) {
        const bf16_t* bbase = base + ((size_t)C << 14) + ((ch * 64 + tx) << 3);
        gram_quadrant(af, bbase, C == R, C == R + 2, R * 128, C * 128,
                      rh, ch, tx, q, rowS, Sb, pb);
    }
    flush_rowS(rowS, R * 128, rh, tx, q, Sb);
}

// ---------------- finalize ----------------
__global__ void fin_ins_k(const float* __restrict__ S_ins, const float* __restrict__ pos_ins,
                          float* __restrict__ acc) {
    int i = blockIdx.x * 256 + threadIdx.x;
    float v = __logf(S_ins[i]) + 10.0f - pos_ins[i];
    int lane = threadIdx.x & 63, wave = threadIdx.x >> 6;
#pragma unroll
    for (int off = 32; off >= 1; off >>= 1) v += __shfl_down(v, off, 64);
    __shared__ float ps[4];
    if (lane == 0) ps[wave] = v;
    __syncthreads();
    if (threadIdx.x == 0) atomicAdd(&acc[0], ps[0] + ps[1] + ps[2] + ps[3]);
}

__global__ void fin_patch_k(const float* __restrict__ Sp, const float* __restrict__ posp,
                            const int* __restrict__ c1, const int* __restrict__ c2,
                            float* __restrict__ acc) {
    int idx = blockIdx.x * 256 + threadIdx.x;   // over BP*NP
    int b = idx >> 9, i = idx & 511;
    int cnt = (i < P) ? c1[b * P + i] : c2[b * P + i - P];
    float v = (cnt != 0) ? (__logf(Sp[idx]) + 10.0f - posp[idx]) : 0.f;
    int lane = threadIdx.x & 63, wave = threadIdx.x >> 6;
#pragma unroll
    for (int off = 32; off >= 1; off >>= 1) v += __shfl_down(v, off, 64);
    __shared__ float ps[4];
    if (lane == 0) ps[wave] = v;
    __syncthreads();
    if (threadIdx.x == 0) atomicAdd(&acc[1], ps[0] + ps[1] + ps[2] + ps[3]);
}

__global__ void final_k(const int* __restrict__ c1, const int* __restrict__ c2,
                        const float* __restrict__ acc, float* __restrict__ out) {
    int t = threadIdx.x;
    int cnt = 0;
    for (int i = t; i < BP * P; i += 256) {
        cnt += (c1[i] != 0) ? 1 : 0;
        cnt += (c2[i] != 0) ? 1 : 0;
    }
    float v = (float)cnt;
    int lane = t & 63, wave = t >> 6;
#pragma unroll
    for (int off = 32; off >= 1; off >>= 1) v += __shfl_down(v, off, 64);
    __shared__ float ps[4];
    if (lane == 0) ps[wave] = v;
    __syncthreads();
    if (t == 0) {
        float n_valid = ps[0] + ps[1] + ps[2] + ps[3];
        out[0] = acc[0] * (1.0f / (float)N_INS) + acc[1] / n_valid;
    }
}

// ---------------- launch ----------------
extern "C" void kernel_launch(void* const* d_in, const int* in_sizes, int n_in,
                              void* d_out, int out_size, void* d_ws, size_t ws_size,
                              hipStream_t stream) {
    const float* v1i = (const float*)d_in[0];
    const float* v2i = (const float*)d_in[1];
    const float* v1p = (const float*)d_in[2];
    const float* v2p = (const float*)d_in[3];
    const int* c1 = (const int*)d_in[4];
    const int* c2 = (const int*)d_in[5];
    float* ws = (float*)d_ws;
    float* out = (float*)d_out;
    bf16_t* embI = (bf16_t*)((char*)d_ws + EMB_I_BYTE);
    bf16_t* embP = (bf16_t*)((char*)d_ws + EMB_P_BYTE);

    hipMemsetAsync(ws, 0, WS_ZERO_FLOATS * sizeof(float), stream);

    norm_ins_k<<<N_INS / 4, 256, 0, stream>>>(v1i, v2i, embI);
    norm_patch_k<<<BP * 2 * 4, 256, 0, stream>>>(v1p, v2p, embP);

    ins_panel_k<<<1088, 256, 0, stream>>>(embI, ws + WS_S, ws + WS_POS);
    patch_panel_k<<<BP * 4, 256, 0, stream>>>(embP, ws + WS_SP, ws + WS_PP);

    fin_ins_k<<<N_INS / 256, 256, 0, stream>>>(ws + WS_S, ws + WS_POS, ws + WS_ACC);
    fin_patch_k<<<(BP * NP) / 256, 256, 0, stream>>>(ws + WS_SP, ws + WS_PP, c1, c2, ws + WS_ACC);
    final_k<<<1, 256, 0, stream>>>(c1, c2, ws + WS_ACC, out);
}